// Round 2
// baseline (439.816 us; speedup 1.0000x reference)
//
#include <hip/hip_runtime.h>

#define GN_EPS 1e-5f

// Problem constants (fixed by setup_inputs): N=131072, U=256, B=64
constexpr int U      = 256;
constexpr int NPG    = 2048;          // nodes per graph = 131072/64
constexpr int NGRAPH = 64;
constexpr int UPB    = 32;            // units per block
constexpr int GPB    = UPB / 4;       // 8 float4 groups per block
constexpr int NSLICE = U / UPB;       // 8 slices per graph
constexpr int BLK    = 512;           // threads per block
constexpr int ROWS   = BLK / GPB;     // 64 rows per iteration
constexpr int ITERS  = NPG / ROWS;    // 32 iterations

__global__ __launch_bounds__(BLK) void graphnorm_kernel(
    const float* __restrict__ x,
    const float* __restrict__ gamma,
    const float* __restrict__ beta,
    float* __restrict__ out)
{
    const int slice = blockIdx.x & (NSLICE - 1);
    const int graph = blockIdx.x / NSLICE;
    const int t     = threadIdx.x;
    const int grp   = t & (GPB - 1);      // which float4 group (4 units)
    const int r0    = t >> 3;             // row offset 0..63
    const int col   = slice * UPB + grp * 4;
    const size_t base = (size_t)graph * NPG * U + (size_t)col;

    // ---- Phase 1: per-thread partial sums over rows r0, r0+64, ... ----
    float4 s = make_float4(0.f, 0.f, 0.f, 0.f);
    float4 q = make_float4(0.f, 0.f, 0.f, 0.f);
#pragma unroll 8
    for (int i = 0; i < ITERS; ++i) {
        const int row = r0 + i * ROWS;
        const float4 v = *reinterpret_cast<const float4*>(x + base + (size_t)row * U);
        s.x += v.x; s.y += v.y; s.z += v.z; s.w += v.w;
        q.x += v.x * v.x; q.y += v.y * v.y; q.z += v.z * v.z; q.w += v.w * v.w;
    }

    // ---- Wave reduce: combine lanes with the same (lane & 7) ----
#pragma unroll
    for (int m = 8; m <= 32; m <<= 1) {
        s.x += __shfl_xor(s.x, m); s.y += __shfl_xor(s.y, m);
        s.z += __shfl_xor(s.z, m); s.w += __shfl_xor(s.w, m);
        q.x += __shfl_xor(q.x, m); q.y += __shfl_xor(q.y, m);
        q.z += __shfl_xor(q.z, m); q.w += __shfl_xor(q.w, m);
    }

    __shared__ float4 ssum[BLK / 64][GPB];
    __shared__ float4 ssq [BLK / 64][GPB];
    __shared__ float4 smean[GPB];
    __shared__ float4 sinv [GPB];

    const int wave = t >> 6;
    const int lane = t & 63;
    if (lane < GPB) {
        ssum[wave][lane] = s;
        ssq [wave][lane] = q;
    }
    __syncthreads();

    // ---- Cross-wave reduce (first wave only): 8 waves x 8 groups = 64 values ----
    if (t < 64) {
        const int g = t & 7;
        const int w = t >> 3;
        float4 s2 = ssum[w][g];
        float4 q2 = ssq [w][g];
#pragma unroll
        for (int m = 8; m <= 32; m <<= 1) {
            s2.x += __shfl_xor(s2.x, m); s2.y += __shfl_xor(s2.y, m);
            s2.z += __shfl_xor(s2.z, m); s2.w += __shfl_xor(s2.w, m);
            q2.x += __shfl_xor(q2.x, m); q2.y += __shfl_xor(q2.y, m);
            q2.z += __shfl_xor(q2.z, m); q2.w += __shfl_xor(q2.w, m);
        }
        if (t < GPB) {
            const float invn = 1.0f / (float)NPG;
            float4 mean, inv;
            mean.x = s2.x * invn; mean.y = s2.y * invn;
            mean.z = s2.z * invn; mean.w = s2.w * invn;
            float vx = fmaxf(q2.x * invn - mean.x * mean.x, 0.f);
            float vy = fmaxf(q2.y * invn - mean.y * mean.y, 0.f);
            float vz = fmaxf(q2.z * invn - mean.z * mean.z, 0.f);
            float vw = fmaxf(q2.w * invn - mean.w * mean.w, 0.f);
            inv.x = 1.0f / (sqrtf(vx) + GN_EPS);
            inv.y = 1.0f / (sqrtf(vy) + GN_EPS);
            inv.z = 1.0f / (sqrtf(vz) + GN_EPS);
            inv.w = 1.0f / (sqrtf(vw) + GN_EPS);
            smean[t] = mean;
            sinv [t] = inv;
        }
    }
    __syncthreads();

    const float4 mean = smean[grp];
    const float4 inv  = sinv [grp];

    // ---- Phase 2: normalize + affine ----
#pragma unroll 4
    for (int i = 0; i < ITERS; ++i) {
        const int row = r0 + i * ROWS;
        const size_t off = base + (size_t)row * U;
        const float4 v  = *reinterpret_cast<const float4*>(x + off);
        const float4 g4 = *reinterpret_cast<const float4*>(gamma + off);
        const float4 b4 = *reinterpret_cast<const float4*>(beta + off);
        float4 o;
        o.x = fmaf(g4.x, (v.x - mean.x) * inv.x, b4.x);
        o.y = fmaf(g4.y, (v.y - mean.y) * inv.y, b4.y);
        o.z = fmaf(g4.z, (v.z - mean.z) * inv.z, b4.z);
        o.w = fmaf(g4.w, (v.w - mean.w) * inv.w, b4.w);
        *reinterpret_cast<float4*>(out + off) = o;
    }
}

extern "C" void kernel_launch(void* const* d_in, const int* in_sizes, int n_in,
                              void* d_out, int out_size, void* d_ws, size_t ws_size,
                              hipStream_t stream) {
    const float* x     = (const float*)d_in[0];
    const float* gamma = (const float*)d_in[1];
    const float* beta  = (const float*)d_in[2];
    float* out = (float*)d_out;
    (void)in_sizes; (void)n_in; (void)out_size; (void)d_ws; (void)ws_size;

    const int grid = NGRAPH * NSLICE;  // 512 blocks
    graphnorm_kernel<<<grid, BLK, 0, stream>>>(x, gamma, beta, out);
}

// Round 3
// 414.871 us; speedup vs baseline: 1.0601x; 1.0601x over previous
//
#include <hip/hip_runtime.h>

#define GN_EPS 1e-5f

// Problem constants (fixed by setup_inputs): N=131072, U=256, B=64
constexpr int U       = 256;                 // units (row length, 1 KB = 64 lanes x 16 B)
constexpr int NPG     = 2048;                // nodes (rows) per graph
constexpr int NGRAPH  = 64;
constexpr int UF4     = U / 4;               // 64 float4 per row

// Kernel 1: partial stats
constexpr int CH      = 16;                  // row-chunks per graph
constexpr int RPC     = NPG / CH;            // 128 rows per chunk
constexpr int K1_BLK  = 256;                 // 4 waves
constexpr int K1_WAVES = K1_BLK / 64;
constexpr int K1_ITERS = RPC / K1_WAVES;     // 32 rows per wave

// Kernel 3: normalize
constexpr int CH3     = 32;                  // row-chunks per graph
constexpr int RPC3    = NPG / CH3;           // 64 rows per chunk
constexpr int K3_BLK  = 256;
constexpr int K3_ITERS = (RPC3 * UF4) / K3_BLK; // 16 float4 per thread

// Workspace layout (floats):
//   ws_sum : NGRAPH*CH*U      (per-chunk column sums)
//   ws_sq  : NGRAPH*CH*U      (per-chunk column sumsq)
//   mean   : NGRAPH*U
//   inv    : NGRAPH*U
constexpr size_t WS_SUM_OFF  = 0;
constexpr size_t WS_SQ_OFF   = (size_t)NGRAPH * CH * U;
constexpr size_t WS_MEAN_OFF = WS_SQ_OFF + (size_t)NGRAPH * CH * U;
constexpr size_t WS_INV_OFF  = WS_MEAN_OFF + (size_t)NGRAPH * U;

// ---------- K1: per-(graph, chunk) partial column sums over 128 full rows ----------
__global__ __launch_bounds__(K1_BLK) void gn_partial(
    const float* __restrict__ x, float* __restrict__ ws)
{
    const int chunk = blockIdx.x & (CH - 1);
    const int graph = blockIdx.x / CH;
    const int t     = threadIdx.x;
    const int wave  = t >> 6;
    const int lane  = t & 63;                // lane <-> float4 column group

    // wave w reads rows w, w+4, w+8, ... each as one contiguous 1 KB wave-load
    const size_t row0 = (size_t)graph * NPG + (size_t)chunk * RPC + wave;
    const float4* xr = reinterpret_cast<const float4*>(x) + row0 * UF4 + lane;

    float4 s = make_float4(0.f, 0.f, 0.f, 0.f);
    float4 q = make_float4(0.f, 0.f, 0.f, 0.f);
#pragma unroll 8
    for (int i = 0; i < K1_ITERS; ++i) {
        const float4 v = xr[(size_t)i * K1_WAVES * UF4];
        s.x += v.x; s.y += v.y; s.z += v.z; s.w += v.w;
        q.x += v.x * v.x; q.y += v.y * v.y; q.z += v.z * v.z; q.w += v.w * v.w;
    }

    __shared__ float4 ssum[K1_WAVES][64];
    __shared__ float4 ssq [K1_WAVES][64];
    ssum[wave][lane] = s;
    ssq [wave][lane] = q;
    __syncthreads();

    if (t < 64) {
        float4 s2 = ssum[0][t];
        float4 q2 = ssq [0][t];
#pragma unroll
        for (int w = 1; w < K1_WAVES; ++w) {
            const float4 a = ssum[w][t];
            const float4 b = ssq [w][t];
            s2.x += a.x; s2.y += a.y; s2.z += a.z; s2.w += a.w;
            q2.x += b.x; q2.y += b.y; q2.z += b.z; q2.w += b.w;
        }
        const size_t o = ((size_t)graph * CH + chunk) * UF4 + t;
        reinterpret_cast<float4*>(ws + WS_SUM_OFF)[o] = s2;
        reinterpret_cast<float4*>(ws + WS_SQ_OFF )[o] = q2;
    }
}

// ---------- K2: reduce CH partials -> mean, 1/(std+eps) per (graph, unit) ----------
__global__ __launch_bounds__(U) void gn_finalize(float* __restrict__ ws)
{
    const int graph = blockIdx.x;
    const int t     = threadIdx.x;           // unit index

    const float* psum = ws + WS_SUM_OFF + (size_t)graph * CH * U + t;
    const float* psq  = ws + WS_SQ_OFF  + (size_t)graph * CH * U + t;
    float s = 0.f, q = 0.f;
#pragma unroll
    for (int c = 0; c < CH; ++c) {
        s += psum[(size_t)c * U];
        q += psq [(size_t)c * U];
    }
    const float invn = 1.0f / (float)NPG;
    const float mean = s * invn;
    const float var  = fmaxf(q * invn - mean * mean, 0.f);
    ws[WS_MEAN_OFF + (size_t)graph * U + t] = mean;
    ws[WS_INV_OFF  + (size_t)graph * U + t] = 1.0f / (sqrtf(var) + GN_EPS);
}

// ---------- K3: normalize + affine, streaming ----------
__global__ __launch_bounds__(K3_BLK) void gn_normalize(
    const float* __restrict__ x,
    const float* __restrict__ gamma,
    const float* __restrict__ beta,
    const float* __restrict__ ws,
    float* __restrict__ out)
{
    const int chunk = blockIdx.x & (CH3 - 1);
    const int graph = blockIdx.x / CH3;
    const int t     = threadIdx.x;

    __shared__ float4 smean[UF4];
    __shared__ float4 sinv [UF4];
    if (t < UF4) {
        smean[t] = reinterpret_cast<const float4*>(ws + WS_MEAN_OFF + (size_t)graph * U)[t];
        sinv [t] = reinterpret_cast<const float4*>(ws + WS_INV_OFF  + (size_t)graph * U)[t];
    }
    __syncthreads();

    const size_t row0 = (size_t)graph * NPG + (size_t)chunk * RPC3;
    const size_t f4base = row0 * UF4;
    const float4* xv = reinterpret_cast<const float4*>(x)     + f4base;
    const float4* gv = reinterpret_cast<const float4*>(gamma) + f4base;
    const float4* bv = reinterpret_cast<const float4*>(beta)  + f4base;
    float4*       ov = reinterpret_cast<float4*>(out)         + f4base;

#pragma unroll 4
    for (int i = 0; i < K3_ITERS; ++i) {
        const int idx = i * K3_BLK + t;      // 0 .. 4095
        const int f4  = idx & (UF4 - 1);     // column group
        const float4 v  = xv[idx];
        const float4 g4 = gv[idx];
        const float4 b4 = bv[idx];
        const float4 m  = smean[f4];
        const float4 iv = sinv [f4];
        float4 o;
        o.x = fmaf(g4.x, (v.x - m.x) * iv.x, b4.x);
        o.y = fmaf(g4.y, (v.y - m.y) * iv.y, b4.y);
        o.z = fmaf(g4.z, (v.z - m.z) * iv.z, b4.z);
        o.w = fmaf(g4.w, (v.w - m.w) * iv.w, b4.w);
        ov[idx] = o;
    }
}

extern "C" void kernel_launch(void* const* d_in, const int* in_sizes, int n_in,
                              void* d_out, int out_size, void* d_ws, size_t ws_size,
                              hipStream_t stream) {
    const float* x     = (const float*)d_in[0];
    const float* gamma = (const float*)d_in[1];
    const float* beta  = (const float*)d_in[2];
    float* out = (float*)d_out;
    float* ws  = (float*)d_ws;
    (void)in_sizes; (void)n_in; (void)out_size; (void)ws_size;

    gn_partial <<<NGRAPH * CH,  K1_BLK, 0, stream>>>(x, ws);
    gn_finalize<<<NGRAPH,       U,      0, stream>>>(ws);
    gn_normalize<<<NGRAPH * CH3, K3_BLK, 0, stream>>>(x, gamma, beta, ws, out);
}

// Round 4
// 388.945 us; speedup vs baseline: 1.1308x; 1.0667x over previous
//
#include <hip/hip_runtime.h>

#define GN_EPS 1e-5f

typedef float f32x4 __attribute__((ext_vector_type(4)));

// Problem constants (fixed by setup_inputs): N=131072, U=256, B=64
constexpr int U       = 256;                 // units (row length, 1 KB = 64 lanes x 16 B)
constexpr int NPG     = 2048;                // nodes (rows) per graph
constexpr int NGRAPH  = 64;
constexpr int UF4     = U / 4;               // 64 float4 per row

// Kernel 1: partial stats
constexpr int CH      = 16;                  // row-chunks per graph
constexpr int RPC     = NPG / CH;            // 128 rows per chunk
constexpr int K1_BLK  = 256;                 // 4 waves
constexpr int K1_WAVES = K1_BLK / 64;
constexpr int K1_ITERS = RPC / K1_WAVES;     // 32 rows per wave

// Kernel 3: normalize
constexpr int CH3     = 64;                  // row-chunks per graph -> 4096 blocks
constexpr int RPC3    = NPG / CH3;           // 32 rows per chunk
constexpr int K3_BLK  = 256;
constexpr int K3_ITERS = (RPC3 * UF4) / K3_BLK; // 8 float4 per thread

// Workspace layout (floats), total ~2.1 MB:
constexpr size_t WS_SUM_OFF  = 0;
constexpr size_t WS_SQ_OFF   = (size_t)NGRAPH * CH * U;
constexpr size_t WS_MEAN_OFF = WS_SQ_OFF + (size_t)NGRAPH * CH * U;
constexpr size_t WS_INV_OFF  = WS_MEAN_OFF + (size_t)NGRAPH * U;

// ---------- K1: per-(graph, chunk) partial column sums over 128 full rows ----------
__global__ __launch_bounds__(K1_BLK) void gn_partial(
    const float* __restrict__ x, float* __restrict__ ws)
{
    const int chunk = blockIdx.x & (CH - 1);
    const int graph = blockIdx.x / CH;
    const int t     = threadIdx.x;
    const int wave  = t >> 6;
    const int lane  = t & 63;                // lane <-> float4 column group

    // wave w reads rows w, w+4, w+8, ... each as one contiguous 1 KB wave-load
    const size_t row0 = (size_t)graph * NPG + (size_t)chunk * RPC + wave;
    const f32x4* xr = reinterpret_cast<const f32x4*>(x) + row0 * UF4 + lane;

    f32x4 s = (f32x4)0.f;
    f32x4 q = (f32x4)0.f;
#pragma unroll 8
    for (int i = 0; i < K1_ITERS; ++i) {
        const f32x4 v = xr[(size_t)i * K1_WAVES * UF4];
        s += v;
        q += v * v;
    }

    __shared__ f32x4 ssum[K1_WAVES][64];
    __shared__ f32x4 ssq [K1_WAVES][64];
    ssum[wave][lane] = s;
    ssq [wave][lane] = q;
    __syncthreads();

    if (t < 64) {
        f32x4 s2 = ssum[0][t];
        f32x4 q2 = ssq [0][t];
#pragma unroll
        for (int w = 1; w < K1_WAVES; ++w) {
            s2 += ssum[w][t];
            q2 += ssq [w][t];
        }
        const size_t o = ((size_t)graph * CH + chunk) * UF4 + t;
        reinterpret_cast<f32x4*>(ws + WS_SUM_OFF)[o] = s2;
        reinterpret_cast<f32x4*>(ws + WS_SQ_OFF )[o] = q2;
    }
}

// ---------- K2: reduce CH partials -> mean, 1/(std+eps) per (graph, unit) ----------
__global__ __launch_bounds__(U) void gn_finalize(float* __restrict__ ws)
{
    const int graph = blockIdx.x;
    const int t     = threadIdx.x;           // unit index

    const float* psum = ws + WS_SUM_OFF + (size_t)graph * CH * U + t;
    const float* psq  = ws + WS_SQ_OFF  + (size_t)graph * CH * U + t;
    float s = 0.f, q = 0.f;
#pragma unroll
    for (int c = 0; c < CH; ++c) {
        s += psum[(size_t)c * U];
        q += psq [(size_t)c * U];
    }
    const float invn = 1.0f / (float)NPG;
    const float mean = s * invn;
    const float var  = fmaxf(q * invn - mean * mean, 0.f);
    ws[WS_MEAN_OFF + (size_t)graph * U + t] = mean;
    ws[WS_INV_OFF  + (size_t)graph * U + t] = 1.0f / (sqrtf(var) + GN_EPS);
}

// ---------- K3: normalize + affine, pure streaming, reg-resident stats ----------
__global__ __launch_bounds__(K3_BLK) void gn_normalize(
    const float* __restrict__ x,
    const float* __restrict__ gamma,
    const float* __restrict__ beta,
    const float* __restrict__ ws,
    float* __restrict__ out)
{
    const int chunk = blockIdx.x & (CH3 - 1);
    const int graph = blockIdx.x / CH3;
    const int t     = threadIdx.x;

    // Since K3_BLK % 64 == 0, thread t always touches float4-column (t & 63):
    // stats are loop-invariant registers, no LDS, no barrier.
    const int f4 = t & (UF4 - 1);
    const f32x4 m  = reinterpret_cast<const f32x4*>(ws + WS_MEAN_OFF + (size_t)graph * U)[f4];
    const f32x4 iv = reinterpret_cast<const f32x4*>(ws + WS_INV_OFF  + (size_t)graph * U)[f4];

    const size_t f4base = ((size_t)graph * NPG + (size_t)chunk * RPC3) * UF4;
    const f32x4* xv = reinterpret_cast<const f32x4*>(x)     + f4base;
    const f32x4* gv = reinterpret_cast<const f32x4*>(gamma) + f4base;
    const f32x4* bv = reinterpret_cast<const f32x4*>(beta)  + f4base;
    f32x4*       ov = reinterpret_cast<f32x4*>(out)         + f4base;

#pragma unroll 4
    for (int i = 0; i < K3_ITERS; ++i) {
        const int idx = i * K3_BLK + t;
        const f32x4 v  = xv[idx];                               // normal: L3-hot from K1
        const f32x4 g4 = __builtin_nontemporal_load(gv + idx);  // single-use streams
        const f32x4 b4 = __builtin_nontemporal_load(bv + idx);
        const f32x4 o  = g4 * ((v - m) * iv) + b4;
        __builtin_nontemporal_store(o, ov + idx);               // don't evict reads
    }
}

extern "C" void kernel_launch(void* const* d_in, const int* in_sizes, int n_in,
                              void* d_out, int out_size, void* d_ws, size_t ws_size,
                              hipStream_t stream) {
    const float* x     = (const float*)d_in[0];
    const float* gamma = (const float*)d_in[1];
    const float* beta  = (const float*)d_in[2];
    float* out = (float*)d_out;
    float* ws  = (float*)d_ws;
    (void)in_sizes; (void)n_in; (void)out_size; (void)ws_size;

    gn_partial  <<<NGRAPH * CH,  K1_BLK, 0, stream>>>(x, ws);
    gn_finalize <<<NGRAPH,       U,      0, stream>>>(ws);
    gn_normalize<<<NGRAPH * CH3, K3_BLK, 0, stream>>>(x, gamma, beta, ws, out);
}